// Round 1
// baseline (463.589 us; speedup 1.0000x reference)
//
#include <hip/hip_runtime.h>

#define N_NODES 100000
#define N_EDGES 3200000
#define F_IN 128
#define F_OUT 16

// ws layout: dinv (N floats) at byte 0; h (N*F_OUT floats) at byte OFF_H
#define OFF_H (1u << 19)  // 512 KiB > 400 KB deg array

// K1: deg starts at 1.0 (self-loop weight)
__global__ void k_init_deg(float* __restrict__ deg) {
    int i = blockIdx.x * blockDim.x + threadIdx.x;
    if (i < N_NODES) deg[i] = 1.0f;
}

// K2: deg[col[e]] += w[e]
__global__ void k_accum_deg(const int* __restrict__ col,
                            const float* __restrict__ ew,
                            float* __restrict__ deg) {
    int e = blockIdx.x * blockDim.x + threadIdx.x;
    if (e < N_EDGES) atomicAdd(&deg[col[e]], ew[e]);
}

// K3: dinv = rsqrt(deg)  (deg >= 1 always; in-place)
__global__ void k_dinv(float* __restrict__ deg) {
    int i = blockIdx.x * blockDim.x + threadIdx.x;
    if (i < N_NODES) deg[i] = rsqrtf(deg[i]);
}

// K4: h = x @ W  and  out = b + h * dinv^2  (self-loop contribution)
// 256 threads = 16 rows/block, lane j = output feature; W staged in LDS (8 KB)
__global__ void k_gemm_init(const float* __restrict__ x,
                            const float* __restrict__ W,
                            const float* __restrict__ b,
                            const float* __restrict__ dinv,
                            float* __restrict__ h,
                            float* __restrict__ out) {
    __shared__ float Ws[F_IN * F_OUT];
    int tid = threadIdx.x;
    for (int i = tid; i < F_IN * F_OUT; i += 256) Ws[i] = W[i];
    __syncthreads();

    int n = blockIdx.x * 16 + (tid >> 4);
    int j = tid & 15;
    if (n >= N_NODES) return;

    const float4* xr = (const float4*)(x + (size_t)n * F_IN);
    float acc = 0.0f;
#pragma unroll
    for (int k4 = 0; k4 < F_IN / 4; ++k4) {
        float4 xv = xr[k4];
        int k = k4 * 4;
        acc += xv.x * Ws[(k + 0) * F_OUT + j];
        acc += xv.y * Ws[(k + 1) * F_OUT + j];
        acc += xv.z * Ws[(k + 2) * F_OUT + j];
        acc += xv.w * Ws[(k + 3) * F_OUT + j];
    }
    h[n * F_OUT + j] = acc;
    float di = dinv[n];
    out[n * F_OUT + j] = b[j] + acc * di * di;
}

// K5: scatter — 16 lanes per edge, lane j handles feature j
__global__ void k_scatter(const int* __restrict__ row,
                          const int* __restrict__ col,
                          const float* __restrict__ ew,
                          const float* __restrict__ dinv,
                          const float* __restrict__ h,
                          float* __restrict__ out) {
    long long tid = (long long)blockIdx.x * blockDim.x + threadIdx.x;
    int e = (int)(tid >> 4);
    int j = (int)(tid & 15);
    if (e >= N_EDGES) return;
    int r = row[e];
    int c = col[e];
    float norm = dinv[r] * ew[e] * dinv[c];
    atomicAdd(&out[(size_t)c * F_OUT + j], h[(size_t)r * F_OUT + j] * norm);
}

extern "C" void kernel_launch(void* const* d_in, const int* in_sizes, int n_in,
                              void* d_out, int out_size, void* d_ws, size_t ws_size,
                              hipStream_t stream) {
    const float* x  = (const float*)d_in[0];
    const int*   ei = (const int*)d_in[1];   // [2, N_EDGES] int32
    const float* ew = (const float*)d_in[2];
    const float* W  = (const float*)d_in[3];
    const float* b  = (const float*)d_in[4];
    float* out = (float*)d_out;

    const int* row = ei;            // edge_index[0] = source
    const int* col = ei + N_EDGES;  // edge_index[1] = destination

    float* dinv = (float*)d_ws;
    float* h    = (float*)((char*)d_ws + OFF_H);

    dim3 blk(256);
    k_init_deg<<<(N_NODES + 255) / 256, blk, 0, stream>>>(dinv);
    k_accum_deg<<<(N_EDGES + 255) / 256, blk, 0, stream>>>(col, ew, dinv);
    k_dinv<<<(N_NODES + 255) / 256, blk, 0, stream>>>(dinv);
    k_gemm_init<<<(N_NODES + 15) / 16, blk, 0, stream>>>(x, W, b, dinv, h, out);

    long long total = (long long)N_EDGES * F_OUT;
    k_scatter<<<(unsigned)((total + 255) / 256), blk, 0, stream>>>(row, col, ew, dinv, h, out);
}